// Round 5
// baseline (55.585 us; speedup 1.0000x reference)
//
#include <hip/hip_runtime.h>
#include <stdint.h>

// BaseRenderer: NeRF-style compositing with per-ray depth sort.
// One wave per ray-iteration, 2 samples/lane. Persistent waves (8 rays each),
// 1-deep software pipeline with all-register staging (ping-pong RayRegs),
// zero barriers (all LDS is wave-private), compiler-managed waitcnts.

typedef unsigned long long u64;

// ---------------- DPP helpers ----------------
template<int CTRL, int RM>
__device__ __forceinline__ float updpp_f(float oldv, float src) {
    return __uint_as_float((uint32_t)__builtin_amdgcn_update_dpp(
        (int)__float_as_uint(oldv), (int)__float_as_uint(src), CTRL, RM, 0xF, false));
}

template<int CTRL>
__device__ __forceinline__ uint32_t dppmov_u(uint32_t v) {
    return (uint32_t)__builtin_amdgcn_mov_dpp((int)v, CTRL, 0xF, 0xF, true);
}

// 6-op DPP reduction; full-wave total lands in lane 63.
__device__ __forceinline__ float red6(float x) {
    x += updpp_f<0x111, 0xF>(0.0f, x);   // row_shr:1
    x += updpp_f<0x112, 0xF>(0.0f, x);   // row_shr:2
    x += updpp_f<0x114, 0xF>(0.0f, x);   // row_shr:4
    x += updpp_f<0x118, 0xF>(0.0f, x);   // row_shr:8
    x += updpp_f<0x142, 0xA>(0.0f, x);   // row_bcast:15 -> rows 1,3
    x += updpp_f<0x143, 0xC>(0.0f, x);   // row_bcast:31 -> rows 2,3
    return x;
}

// ---------------- 32-bit bitonic sort (fast path) ----------------
template<int LJ>
__device__ __forceinline__ uint32_t xp(uint32_t k) {
    if constexpr (LJ == 1)      return dppmov_u<0xB1>(k);    // quad_perm xor1
    else if constexpr (LJ == 2) return dppmov_u<0x4E>(k);    // quad_perm xor2
    else if constexpr (LJ == 8) return dppmov_u<0x128>(k);   // row_ror:8 == xor8
    else return (uint32_t)__shfl_xor((int)k, LJ, 64);        // xor4/16/32 via DS
}

template<int LJ>
__device__ __forceinline__ void cross32(uint32_t& a, uint32_t& b, bool dirbit, int lane) {
    uint32_t pa = xp<LJ>(a);
    uint32_t pb = xp<LJ>(b);
    const bool keepmin = (((lane & LJ) == 0) == dirbit);
    a = ((pa < a) == keepmin) ? pa : a;    // keys unique -> no ties
    b = ((pb < b) == keepmin) ? pb : b;
    if constexpr (LJ > 1) cross32<LJ / 2>(a, b, dirbit, lane);
}

template<int K>
__device__ __forceinline__ void phase32(uint32_t& a, uint32_t& b, int lane) {
    const bool dirbit = ((lane & (K >> 1)) == 0);
    if constexpr (K >= 4) cross32<K / 4>(a, b, dirbit, lane);
    const bool sw = ((b < a) == dirbit);   // intra-lane step
    uint32_t t = a;
    a = sw ? b : a;
    b = sw ? t : b;
}

// ---------------- 64-bit fallback sort ----------------
__device__ __forceinline__ u64 shfl_xor_u64(u64 v, int mask) {
    int lo = __shfl_xor((int)(uint32_t)v, mask, 64);
    int hi = __shfl_xor((int)(uint32_t)(v >> 32), mask, 64);
    return ((u64)(uint32_t)hi << 32) | (uint32_t)lo;
}

// ---------------- per-ray register staging ----------------
struct RayRegs {
    float2 zv, sv;                 // z, sigma (samples 2l, 2l+1)
    float2 r01, r23, r45;          // rgb, original order, 6 floats
    float2 q01, q23, q45;          // instance, original order, 6 floats
};

__device__ __forceinline__ RayRegs load_ray(const float* __restrict__ z,
                                            const float* __restrict__ sg,
                                            const float* __restrict__ rgb,
                                            const float* __restrict__ inst,
                                            int ray, int lane) {
    RayRegs d;
    const size_t rb = (size_t)ray * 128;
    d.zv = ((const float2*)(z  + rb))[lane];
    d.sv = ((const float2*)(sg + rb))[lane];
    const float2* rp = (const float2*)(rgb  + rb * 3) + lane * 3;
    d.r01 = rp[0]; d.r23 = rp[1]; d.r45 = rp[2];
    const float2* ip = (const float2*)(inst + rb * 3) + lane * 3;
    d.q01 = ip[0]; d.q23 = ip[1]; d.q45 = ip[2];
    return d;
}

__device__ __forceinline__ void process(const RayRegs& d, int ray, int lane,
                                        float* __restrict__ lds_w_row,
                                        const float* __restrict__ bg_color,
                                        float* __restrict__ out, int N) {
    constexpr float INF_DIST = 1e10f;
    constexpr float EPS = 1e-10f;
    const size_t rbase = (size_t)ray * 128;

    // bg early (only lane 63 consumes, at the very end) -> latency hidden
    float bg0 = 0.0f, bg1 = 0.0f, bg2 = 0.0f;
    if (lane == 63) {
        const float* bg = bg_color + (size_t)ray * 3;
        bg0 = bg[0]; bg1 = bg[1]; bg2 = bg[2];
    }

    // ---- dyadic check: z == m / 2^21, m < 2^23 (exact for JAX uniform*4) ----
    float k0f = d.zv.x * 2097152.0f;
    float k1f = d.zv.y * 2097152.0f;
    uint32_t m0i = (uint32_t)k0f;
    uint32_t m1i = (uint32_t)k1f;
    bool exact = (k0f == (float)m0i) && (k1f == (float)m1i) &&
                 (m0i < (1u << 23)) && (m1i < (1u << 23));

    uint32_t i0, i1;
    float zs0, zs1;

    if (__ballot(exact) == ~0ull) {
        uint32_t a = (m0i << 7) | (uint32_t)(2 * lane);
        uint32_t b = (m1i << 7) | (uint32_t)(2 * lane + 1);
        phase32<2>(a, b, lane);
        phase32<4>(a, b, lane);
        phase32<8>(a, b, lane);
        phase32<16>(a, b, lane);
        phase32<32>(a, b, lane);
        phase32<64>(a, b, lane);
        phase32<128>(a, b, lane);
        i0 = a & 127u;
        i1 = b & 127u;
        zs0 = (float)(a >> 7) * 0x1p-21f;        // bit-exact z recovery
        zs1 = (float)(b >> 7) * 0x1p-21f;
    } else {
        u64 a = ((u64)__float_as_uint(d.zv.x) << 7) | (u64)(2 * lane);
        u64 b = ((u64)__float_as_uint(d.zv.y) << 7) | (u64)(2 * lane + 1);
        #pragma unroll
        for (int k = 2; k <= 128; k <<= 1) {
            #pragma unroll
            for (int j = k >> 1; j >= 2; j >>= 1) {
                const int lj = j >> 1;
                u64 pa = shfl_xor_u64(a, lj);
                u64 pb = shfl_xor_u64(b, lj);
                const bool keepmin = (((lane & lj) == 0) == ((lane & (k >> 1)) == 0));
                a = ((pa < a) == keepmin) ? pa : a;
                b = ((pb < b) == keepmin) ? pb : b;
            }
            const bool asc = ((lane & (k >> 1)) == 0);
            const bool sw = ((b < a) == asc);
            u64 t = a;
            a = sw ? b : a;
            b = sw ? t : b;
        }
        i0 = (uint32_t)(a & 127u);
        i1 = (uint32_t)(b & 127u);
        zs0 = __uint_as_float((uint32_t)(a >> 7));
        zs1 = __uint_as_float((uint32_t)(b >> 7));
    }

    // ---- gather sigma by original index ----
    float s0a = __shfl(d.sv.x, (int)(i0 >> 1), 64);
    float s0b = __shfl(d.sv.y, (int)(i0 >> 1), 64);
    float s1a = __shfl(d.sv.x, (int)(i1 >> 1), 64);
    float s1b = __shfl(d.sv.y, (int)(i1 >> 1), 64);
    float sg0 = (i0 & 1) ? s0b : s0a;
    float sg1 = (i1 & 1) ? s1b : s1a;

    // ---- dists; lane63 boundary via DPP old=INF ----
    float znx = updpp_f<0x130, 0xF>(INF_DIST, zs0);   // wave_shl:1
    float d0 = zs1 - zs0;
    float d1 = znx - zs1;

    // ---- alpha / transmittance factors ----
    float e0 = __expf(-fmaxf(sg0, 0.0f) * d0);
    float e1 = __expf(-fmaxf(sg1, 0.0f) * d1);
    float a0 = 1.0f - e0;
    float a1 = 1.0f - e1;
    float m0 = 1.0f - a0 + EPS;
    float m1 = 1.0f - a1 + EPS;

    // ---- DPP multiply-scan (inclusive), identity 1.0 ----
    float s = m0 * m1;
    s *= updpp_f<0x111, 0xF>(1.0f, s);
    s *= updpp_f<0x112, 0xF>(1.0f, s);
    s *= updpp_f<0x114, 0xF>(1.0f, s);
    s *= updpp_f<0x118, 0xF>(1.0f, s);
    s *= updpp_f<0x142, 0xA>(1.0f, s);
    s *= updpp_f<0x143, 0xC>(1.0f, s);

    float excl = updpp_f<0x138, 0xF>(1.0f, s);        // wave_shr:1, lane0 -> 1.0

    float t0 = excl;
    float t1 = excl * m0;
    float w0 = a0 * t0;
    float w1 = a1 * t1;

    // ---- w output (sorted order), nontemporal 8B ----
    {
        u64 wbits = ((u64)__float_as_uint(w1) << 32) | (u64)__float_as_uint(w0);
        __builtin_nontemporal_store(wbits, (u64*)(out + (size_t)7 * N + rbase) + lane);
    }

    // ---- inverse permutation via wave-private LDS (no barrier needed) ----
    lds_w_row[i0] = w0;
    lds_w_row[i1] = w1;
    float2 wo = ((const float2*)lds_w_row)[lane];     // compiler inserts lgkmcnt

    // ---- depth partial in sorted domain ----
    float dep = w0 * zs0 + w1 * zs1;

    // ---- weighted rgb / instance from registers (original order) ----
    float cr = wo.x * d.r01.x + wo.y * d.r23.y;
    float cg = wo.x * d.r01.y + wo.y * d.r45.x;
    float cb = wo.x * d.r23.x + wo.y * d.r45.y;
    float k0 = wo.x * d.q01.x + wo.y * d.q23.y;
    float k1 = wo.x * d.q01.y + wo.y * d.q45.x;
    float k2 = wo.x * d.q23.x + wo.y * d.q45.y;

    // ---- DPP reductions; totals land in lane 63 ----
    dep = red6(dep);
    cr  = red6(cr);
    cg  = red6(cg);
    cb  = red6(cb);
    k0  = red6(k0);
    k1  = red6(k1);
    k2  = red6(k2);

    if (lane == 63) {
        float no_hit = s;
        out[(size_t)ray * 3 + 0] = cr + no_hit * bg0;
        out[(size_t)ray * 3 + 1] = cg + no_hit * bg1;
        out[(size_t)ray * 3 + 2] = cb + no_hit * bg2;
        out[(size_t)3 * N + ray] = dep;
        out[(size_t)4 * N + (size_t)ray * 3 + 0] = k0;
        out[(size_t)4 * N + (size_t)ray * 3 + 1] = k1;
        out[(size_t)4 * N + (size_t)ray * 3 + 2] = k2;
    }
}

__global__ __launch_bounds__(256, 4) void render_kernel(
    const float* __restrict__ z_vals,
    const float* __restrict__ sigma_vals,
    const float* __restrict__ rgb_vals,
    const float* __restrict__ inst_vals,
    const float* __restrict__ bg_color,
    float* __restrict__ out,
    int N)
{
    const int lane = threadIdx.x & 63;
    const int wib  = threadIdx.x >> 6;
    const int wid  = blockIdx.x * 4 + wib;
    const int wstride = gridDim.x << 2;          // total waves

    __shared__ float lds_w[4][128];              // wave-private rows, 2 KiB
    float* lds_w_row = lds_w[wib];

    if (wid >= N) return;

    // ---- software-pipelined persistent loop, ping-pong register sets ----
    RayRegs A = load_ray(z_vals, sigma_vals, rgb_vals, inst_vals, wid, lane);
    RayRegs B;
    int r = wid;
    while (true) {
        int rn = r + wstride;
        int rl = (rn < N) ? rn : r;              // clamp: cheap L2 re-read on last iter
        B = load_ray(z_vals, sigma_vals, rgb_vals, inst_vals, rl, lane);
        __builtin_amdgcn_sched_barrier(0);       // pin prefetch above compute
        process(A, r, lane, lds_w_row, bg_color, out, N);
        r = rn;
        if (r >= N) break;

        rn = r + wstride;
        rl = (rn < N) ? rn : r;
        A = load_ray(z_vals, sigma_vals, rgb_vals, inst_vals, rl, lane);
        __builtin_amdgcn_sched_barrier(0);
        process(B, r, lane, lds_w_row, bg_color, out, N);
        r = rn;
        if (r >= N) break;
    }
}

extern "C" void kernel_launch(void* const* d_in, const int* in_sizes, int n_in,
                              void* d_out, int out_size, void* d_ws, size_t ws_size,
                              hipStream_t stream)
{
    const float* z    = (const float*)d_in[0];
    const float* sg   = (const float*)d_in[1];
    const float* rgb  = (const float*)d_in[2];
    const float* inst = (const float*)d_in[3];
    const float* bg   = (const float*)d_in[4];
    float* out = (float*)d_out;

    const int S = 128;
    int N = in_sizes[0] / S;                     // 65536
    int blocks = (N + 3) / 4;
    if (blocks > 2048) blocks = 2048;            // persistent: 8192 waves, 8 rays each
    render_kernel<<<blocks, 256, 0, stream>>>(z, sg, rgb, inst, bg, out, N);
}

// Round 6
// 50.997 us; speedup vs baseline: 1.0899x; 1.0899x over previous
//
#include <hip/hip_runtime.h>
#include <stdint.h>

// BaseRenderer: NeRF-style compositing with per-ray depth sort.
// v6: 2 rays per wave. All VMEM (z/sigma VGPR loads + rgb/inst global_load_lds
// staging) for BOTH rays issued at wave start; per-wave s_waitcnt vmcnt(0)
// replaces __syncthreads (all LDS is wave-private -> zero barriers, waves
// fully decoupled). Dense dwordx4 staging, no VGPR payload cost.

typedef unsigned long long u64;

// ---------------- DPP helpers ----------------
template<int CTRL, int RM>
__device__ __forceinline__ float updpp_f(float oldv, float src) {
    return __uint_as_float((uint32_t)__builtin_amdgcn_update_dpp(
        (int)__float_as_uint(oldv), (int)__float_as_uint(src), CTRL, RM, 0xF, false));
}

template<int CTRL>
__device__ __forceinline__ uint32_t dppmov_u(uint32_t v) {
    return (uint32_t)__builtin_amdgcn_mov_dpp((int)v, CTRL, 0xF, 0xF, true);
}

// 6-op DPP reduction; full-wave total lands in lane 63.
__device__ __forceinline__ float red6(float x) {
    x += updpp_f<0x111, 0xF>(0.0f, x);   // row_shr:1
    x += updpp_f<0x112, 0xF>(0.0f, x);   // row_shr:2
    x += updpp_f<0x114, 0xF>(0.0f, x);   // row_shr:4
    x += updpp_f<0x118, 0xF>(0.0f, x);   // row_shr:8
    x += updpp_f<0x142, 0xA>(0.0f, x);   // row_bcast:15 -> rows 1,3
    x += updpp_f<0x143, 0xC>(0.0f, x);   // row_bcast:31 -> rows 2,3
    return x;
}

// ---------------- 32-bit bitonic sort (fast path) ----------------
template<int LJ>
__device__ __forceinline__ uint32_t xp(uint32_t k) {
    if constexpr (LJ == 1)      return dppmov_u<0xB1>(k);    // quad_perm xor1
    else if constexpr (LJ == 2) return dppmov_u<0x4E>(k);    // quad_perm xor2
    else if constexpr (LJ == 8) return dppmov_u<0x128>(k);   // row_ror:8 == xor8
    else return (uint32_t)__shfl_xor((int)k, LJ, 64);        // xor4/16/32 via DS
}

template<int LJ>
__device__ __forceinline__ void cross32(uint32_t& a, uint32_t& b, bool dirbit, int lane) {
    uint32_t pa = xp<LJ>(a);
    uint32_t pb = xp<LJ>(b);
    const bool keepmin = (((lane & LJ) == 0) == dirbit);
    a = ((pa < a) == keepmin) ? pa : a;    // keys unique -> no ties
    b = ((pb < b) == keepmin) ? pb : b;
    if constexpr (LJ > 1) cross32<LJ / 2>(a, b, dirbit, lane);
}

template<int K>
__device__ __forceinline__ void phase32(uint32_t& a, uint32_t& b, int lane) {
    const bool dirbit = ((lane & (K >> 1)) == 0);
    if constexpr (K >= 4) cross32<K / 4>(a, b, dirbit, lane);
    const bool sw = ((b < a) == dirbit);   // intra-lane step
    uint32_t t = a;
    a = sw ? b : a;
    b = sw ? t : b;
}

// ---------------- 64-bit fallback sort ----------------
__device__ __forceinline__ u64 shfl_xor_u64(u64 v, int mask) {
    int lo = __shfl_xor((int)(uint32_t)v, mask, 64);
    int hi = __shfl_xor((int)(uint32_t)(v >> 32), mask, 64);
    return ((u64)(uint32_t)hi << 32) | (uint32_t)lo;
}

#define GLL16(gsrc, ldst) __builtin_amdgcn_global_load_lds(                    \
    (const __attribute__((address_space(1))) void*)(gsrc),                     \
    (__attribute__((address_space(3))) void*)(ldst), 16, 0, 0)

__device__ __forceinline__ void process(float2 zv, float2 sv, int ray, int lane,
                                        float* __restrict__ w_row,
                                        const float* __restrict__ rgb_slab,
                                        const float* __restrict__ inst_slab,
                                        const float* __restrict__ bg_color,
                                        float* __restrict__ out, int N)
{
    constexpr float INF_DIST = 1e10f;
    constexpr float EPS = 1e-10f;
    const size_t rbase = (size_t)ray * 128;

    // bg early (only lane 63 consumes, at the very end) -> latency hidden
    float bg0 = 0.0f, bg1 = 0.0f, bg2 = 0.0f;
    if (lane == 63) {
        const float* bg = bg_color + (size_t)ray * 3;
        bg0 = bg[0]; bg1 = bg[1]; bg2 = bg[2];
    }

    // ---- dyadic check: z == m / 2^21, m < 2^23 (exact for JAX uniform*4) ----
    float k0f = zv.x * 2097152.0f;
    float k1f = zv.y * 2097152.0f;
    uint32_t m0i = (uint32_t)k0f;
    uint32_t m1i = (uint32_t)k1f;
    bool exact = (k0f == (float)m0i) && (k1f == (float)m1i) &&
                 (m0i < (1u << 23)) && (m1i < (1u << 23));

    uint32_t i0, i1;
    float zs0, zs1;

    if (__ballot(exact) == ~0ull) {
        uint32_t a = (m0i << 7) | (uint32_t)(2 * lane);
        uint32_t b = (m1i << 7) | (uint32_t)(2 * lane + 1);
        phase32<2>(a, b, lane);
        phase32<4>(a, b, lane);
        phase32<8>(a, b, lane);
        phase32<16>(a, b, lane);
        phase32<32>(a, b, lane);
        phase32<64>(a, b, lane);
        phase32<128>(a, b, lane);
        i0 = a & 127u;
        i1 = b & 127u;
        zs0 = (float)(a >> 7) * 0x1p-21f;        // bit-exact z recovery
        zs1 = (float)(b >> 7) * 0x1p-21f;
    } else {
        u64 a = ((u64)__float_as_uint(zv.x) << 7) | (u64)(2 * lane);
        u64 b = ((u64)__float_as_uint(zv.y) << 7) | (u64)(2 * lane + 1);
        #pragma unroll
        for (int k = 2; k <= 128; k <<= 1) {
            #pragma unroll
            for (int j = k >> 1; j >= 2; j >>= 1) {
                const int lj = j >> 1;
                u64 pa = shfl_xor_u64(a, lj);
                u64 pb = shfl_xor_u64(b, lj);
                const bool keepmin = (((lane & lj) == 0) == ((lane & (k >> 1)) == 0));
                a = ((pa < a) == keepmin) ? pa : a;
                b = ((pb < b) == keepmin) ? pb : b;
            }
            const bool asc = ((lane & (k >> 1)) == 0);
            const bool sw = ((b < a) == asc);
            u64 t = a;
            a = sw ? b : a;
            b = sw ? t : b;
        }
        i0 = (uint32_t)(a & 127u);
        i1 = (uint32_t)(b & 127u);
        zs0 = __uint_as_float((uint32_t)(a >> 7));
        zs1 = __uint_as_float((uint32_t)(b >> 7));
    }

    // ---- gather sigma by original index ----
    float s0a = __shfl(sv.x, (int)(i0 >> 1), 64);
    float s0b = __shfl(sv.y, (int)(i0 >> 1), 64);
    float s1a = __shfl(sv.x, (int)(i1 >> 1), 64);
    float s1b = __shfl(sv.y, (int)(i1 >> 1), 64);
    float sg0 = (i0 & 1) ? s0b : s0a;
    float sg1 = (i1 & 1) ? s1b : s1a;

    // ---- dists; lane63 boundary via DPP old=INF ----
    float znx = updpp_f<0x130, 0xF>(INF_DIST, zs0);   // wave_shl:1
    float d0 = zs1 - zs0;
    float d1 = znx - zs1;

    // ---- alpha / transmittance factors ----
    float e0 = __expf(-fmaxf(sg0, 0.0f) * d0);
    float e1 = __expf(-fmaxf(sg1, 0.0f) * d1);
    float a0 = 1.0f - e0;
    float a1 = 1.0f - e1;
    float m0 = 1.0f - a0 + EPS;
    float m1 = 1.0f - a1 + EPS;

    // ---- DPP multiply-scan (inclusive), identity 1.0 ----
    float s = m0 * m1;
    s *= updpp_f<0x111, 0xF>(1.0f, s);
    s *= updpp_f<0x112, 0xF>(1.0f, s);
    s *= updpp_f<0x114, 0xF>(1.0f, s);
    s *= updpp_f<0x118, 0xF>(1.0f, s);
    s *= updpp_f<0x142, 0xA>(1.0f, s);
    s *= updpp_f<0x143, 0xC>(1.0f, s);

    float excl = updpp_f<0x138, 0xF>(1.0f, s);        // wave_shr:1, lane0 -> 1.0

    float t0 = excl;
    float t1 = excl * m0;
    float w0 = a0 * t0;
    float w1 = a1 * t1;

    // ---- drain VMEM: guarantees this ray's gll slab is in LDS.            ----
    // Per-wave (no barrier). Everything outstanding was issued >=1200cy ago,
    // so this is ~free. Always-safe (over-waits, never races).
    asm volatile("s_waitcnt vmcnt(0)" ::: "memory");
    __builtin_amdgcn_sched_barrier(0);

    // ---- w output (sorted order), nontemporal 8B, after the drain ----
    {
        u64 wbits = ((u64)__float_as_uint(w1) << 32) | (u64)__float_as_uint(w0);
        __builtin_nontemporal_store(wbits, (u64*)(out + (size_t)7 * N + rbase) + lane);
    }

    // ---- inverse permutation via wave-private LDS (no barrier needed) ----
    w_row[i0] = w0;
    w_row[i1] = w1;
    float2 wo = ((const float2*)w_row)[lane];         // compiler inserts lgkmcnt

    // ---- depth partial in sorted domain ----
    float dep = w0 * zs0 + w1 * zs1;

    // ---- rgb / instance from staged LDS (original order): 6 floats each ----
    const float2* rp2 = (const float2*)&rgb_slab[lane * 6];
    float2 r01 = rp2[0];
    float2 r23 = rp2[1];
    float2 r45 = rp2[2];
    const float2* ip2 = (const float2*)&inst_slab[lane * 6];
    float2 q01 = ip2[0];
    float2 q23 = ip2[1];
    float2 q45 = ip2[2];

    // sample 2l -> (r01.x, r01.y, r23.x); sample 2l+1 -> (r23.y, r45.x, r45.y)
    float cr = wo.x * r01.x + wo.y * r23.y;
    float cg = wo.x * r01.y + wo.y * r45.x;
    float cb = wo.x * r23.x + wo.y * r45.y;
    float k0 = wo.x * q01.x + wo.y * q23.y;
    float k1 = wo.x * q01.y + wo.y * q45.x;
    float k2 = wo.x * q23.x + wo.y * q45.y;

    // ---- DPP reductions; totals land in lane 63 ----
    dep = red6(dep);
    cr  = red6(cr);
    cg  = red6(cg);
    cb  = red6(cb);
    k0  = red6(k0);
    k1  = red6(k1);
    k2  = red6(k2);

    if (lane == 63) {
        float no_hit = s;
        out[(size_t)ray * 3 + 0] = cr + no_hit * bg0;
        out[(size_t)ray * 3 + 1] = cg + no_hit * bg1;
        out[(size_t)ray * 3 + 2] = cb + no_hit * bg2;
        out[(size_t)3 * N + ray] = dep;
        out[(size_t)4 * N + (size_t)ray * 3 + 0] = k0;
        out[(size_t)4 * N + (size_t)ray * 3 + 1] = k1;
        out[(size_t)4 * N + (size_t)ray * 3 + 2] = k2;
    }
}

__global__ __launch_bounds__(256) void render_kernel(
    const float* __restrict__ z_vals,
    const float* __restrict__ sigma_vals,
    const float* __restrict__ rgb_vals,
    const float* __restrict__ inst_vals,
    const float* __restrict__ bg_color,
    float* __restrict__ out,
    int N)
{
    const int lane = threadIdx.x & 63;
    const int wib  = threadIdx.x >> 6;
    const int wid  = blockIdx.x * 4 + wib;

    // Per-wave LDS: 2 rgb slabs + 2 inst slabs (1536B each) + w row (512B).
    __shared__ float lds_rgb[4][2][384];      // 12 KiB
    __shared__ float lds_inst[4][2][384];     // 12 KiB
    __shared__ float lds_w[4][128];           //  2 KiB  -> 26.6 KiB/block

    int ray0 = 2 * wid;
    int ray1 = 2 * wid + 1;
    if (ray0 >= N) return;
    if (ray1 >= N) ray1 = ray0;               // duplicate-safe clamp (barrier-free)

    const size_t rb0 = (size_t)ray0 * 128;
    const size_t rb1 = (size_t)ray1 * 128;

    // ---- issue ALL VMEM for both rays up front ----
    float2 zv0 = ((const float2*)(z_vals     + rb0))[lane];
    float2 sv0 = ((const float2*)(sigma_vals + rb0))[lane];
    float2 zv1 = ((const float2*)(z_vals     + rb1))[lane];
    float2 sv1 = ((const float2*)(sigma_vals + rb1))[lane];

    {
        const char* r0 = (const char*)(rgb_vals  + rb0 * 3);
        const char* i0 = (const char*)(inst_vals + rb0 * 3);
        const char* r1 = (const char*)(rgb_vals  + rb1 * 3);
        const char* i1 = (const char*)(inst_vals + rb1 * 3);
        char* rd0 = (char*)&lds_rgb[wib][0][0];
        char* id0 = (char*)&lds_inst[wib][0][0];
        char* rd1 = (char*)&lds_rgb[wib][1][0];
        char* id1 = (char*)&lds_inst[wib][1][0];
        GLL16(r0 + (size_t)lane * 16, rd0);
        GLL16(i0 + (size_t)lane * 16, id0);
        GLL16(r1 + (size_t)lane * 16, rd1);
        GLL16(i1 + (size_t)lane * 16, id1);
        if (lane < 32) {
            GLL16(r0 + 1024 + (size_t)lane * 16, rd0 + 1024);
            GLL16(i0 + 1024 + (size_t)lane * 16, id0 + 1024);
            GLL16(r1 + 1024 + (size_t)lane * 16, rd1 + 1024);
            GLL16(i1 + 1024 + (size_t)lane * 16, id1 + 1024);
        }
    }
    __builtin_amdgcn_sched_barrier(0);        // pin all issues above compute

    process(zv0, sv0, ray0, lane, lds_w[wib],
            &lds_rgb[wib][0][0], &lds_inst[wib][0][0], bg_color, out, N);
    process(zv1, sv1, ray1, lane, lds_w[wib],
            &lds_rgb[wib][1][0], &lds_inst[wib][1][0], bg_color, out, N);
}

extern "C" void kernel_launch(void* const* d_in, const int* in_sizes, int n_in,
                              void* d_out, int out_size, void* d_ws, size_t ws_size,
                              hipStream_t stream)
{
    const float* z    = (const float*)d_in[0];
    const float* sg   = (const float*)d_in[1];
    const float* rgb  = (const float*)d_in[2];
    const float* inst = (const float*)d_in[3];
    const float* bg   = (const float*)d_in[4];
    float* out = (float*)d_out;

    const int S = 128;
    int N = in_sizes[0] / S;                  // 65536
    int waves = (N + 1) / 2;                  // 2 rays per wave
    int blocks = (waves + 3) / 4;             // 4 waves per 256-thread block
    render_kernel<<<blocks, 256, 0, stream>>>(z, sg, rgb, inst, bg, out, N);
}